// Round 5
// baseline (233.538 us; speedup 1.0000x reference)
//
#include <hip/hip_runtime.h>

typedef unsigned short u16;
typedef __bf16 bf16x8 __attribute__((ext_vector_type(8)));
typedef float f32x4 __attribute__((ext_vector_type(4)));
typedef unsigned short u16x8 __attribute__((ext_vector_type(8)));

#define Bq 4
#define Dq 768
#define Lq 4096
#define Mq (Lq * Bq)   // 16384
#define NK 24          // K=768 / BK=32

__device__ __forceinline__ u16 f2bf(float f) {
    unsigned int u = __builtin_bit_cast(unsigned int, f);
    u += 0x7fffu + ((u >> 16) & 1u);   // RNE
    return (u16)(u >> 16);
}

__device__ __forceinline__ float bf2f(u16 h) {
    return __builtin_bit_cast(float, (unsigned int)h << 16);
}

__device__ __forceinline__ void async16(const void* g, void* l) {
    __builtin_amdgcn_global_load_lds(
        (const __attribute__((address_space(1))) unsigned int*)(unsigned long long)g,
        (__attribute__((address_space(3))) unsigned int*)(unsigned int)(unsigned long long)l,
        16, 0, 0);
}

// ---- prep: fp32 weights -> bf16, zero the 4 pad rows of Vpad/Gpad ----
__global__ __launch_bounds__(256) void prep_kernel(
    const float* __restrict__ Wih, const float* __restrict__ Whh,
    u16* __restrict__ Wihb, u16* __restrict__ Whhb,
    u16* __restrict__ Vpad, u16* __restrict__ Gpad) {
    int i = blockIdx.x * 256 + threadIdx.x;
    if (i < Dq * Dq) {
        Wihb[i] = f2bf(Wih[i]);
        Whhb[i] = f2bf(Whh[i]);
    }
    if (i < Bq * Dq) { Vpad[i] = 0; Gpad[i] = 0; }
}

// ---- transpose x [B,D,L] fp32 -> Xt [(l*B+b), d] bf16 ----
__global__ __launch_bounds__(256) void transpose_kernel(
    const float* __restrict__ x, u16* __restrict__ Xt) {
    __shared__ u16 tile[64][66];
    int b = blockIdx.z, d0 = blockIdx.y * 64, l0 = blockIdx.x * 64;
    int tx = threadIdx.x & 63, ty = threadIdx.x >> 6;
    const float* xp = x + ((size_t)b * Dq + d0) * Lq + l0;
#pragma unroll
    for (int i = 0; i < 16; ++i) {
        int r = i * 4 + ty;
        tile[r][tx] = f2bf(xp[(size_t)r * Lq + tx]);
    }
    __syncthreads();
    u16* xt = Xt + ((size_t)l0 * Bq + b) * Dq + d0;
#pragma unroll
    for (int i = 0; i < 16; ++i) {
        int c = i * 4 + ty;
        xt[(size_t)c * Bq * Dq + tx] = tile[tx][c];
    }
}

// ---- K=768 GEMM, tile 128x96, BK=32, 2-deep pipeline, 1 barrier/iter ----
// acc = A@W^T  (A row-major [M][768] bf16, W [N][768] bf16)
// MODE 0 (pass A): Ub = acc + bih + bhh (bf16); Vpad = relu(Ub) at +4 rows
// MODE 1 (pass B): Gpad = relu(Ub + acc) at +4 rows
// MODE 2 (pass C): Eout[B,D,L] = relu(Ub + acc), transposed via LDS, bf16
// Schedule per iter j: wait vmcnt(0) [j's loads, issued at iter j-1];
// barrier [frees buf (j+1)&1: its readers were iter j-1's MFMAs];
// stage j+1 into freed buffer; ds_read frags of j; MFMA.
template <int MODE>
__global__ __launch_bounds__(256, 4) void gemm_kernel(
    const u16* __restrict__ A, const u16* __restrict__ W,
    const u16* __restrict__ Ub_in, u16* __restrict__ Out0, u16* __restrict__ Out1,
    const float* __restrict__ bih, const float* __restrict__ bhh) {
    __shared__ __align__(16) char smem[28672];   // 2 x (8KB A + 6KB B)

    int tid = threadIdx.x;
    int wave = tid >> 6, lane = tid & 63;
    int wr = wave >> 1, wc = wave & 1;
    int m0 = blockIdx.x * 128, n0 = blockIdx.y * 96;
    int lr = lane & 15, lq = lane >> 4;

    // staging (per async16: 64 lanes cover 16 rows x 32 cols; lane -> row=lane>>2,
    // colseg=lane&3 => LDS dst == uniform base + lane*16B, the HW requirement)
    const u16* ga  = A + (size_t)(m0 + wave * 32 + (lane >> 2)) * Dq + (lane & 3) * 8;
    const u16* gb  = W + (size_t)(n0 + wave * 16 + (lane >> 2)) * Dq + (lane & 3) * 8;
    const u16* gb2 = W + (size_t)(n0 + (4 + wave) * 16 + (lane >> 2)) * Dq + (lane & 3) * 8;
    int aro  = wave * 1024;         // A region: wave's 32 rows (u16 offset)
    int bro  = wave * 512;          // B group `wave` (16 rows)
    int bro2 = (4 + wave) * 512;    // B group 4+wave (waves 0,1 only)

    u16* b0 = (u16*)smem;           // buffer: A[128][32] (4096 u16) + B[96][32] (3072)
    u16* b1 = b0 + 7168;

    auto stage = [&](u16* buf) {
        u16* As = buf;
        u16* Bs = buf + 4096;
        async16(ga,           As + aro);
        async16(ga + 16 * Dq, As + aro + 512);
        async16(gb,           Bs + bro);
        if (wave < 2) async16(gb2, Bs + bro2);
        ga += 32; gb += 32; gb2 += 32;
    };

    f32x4 acc[4][3];
#pragma unroll
    for (int i = 0; i < 4; ++i)
#pragma unroll
        for (int j = 0; j < 3; ++j) acc[i][j] = f32x4{0.f, 0.f, 0.f, 0.f};

    stage(b0);
    u16 *cur = b0, *nxt = b1;

    for (int j = 0; j < NK; ++j) {
        asm volatile("s_waitcnt vmcnt(0)\n\ts_barrier" ::: "memory");
        if (j + 1 < NK) stage(nxt);

        const u16* As = cur;
        const u16* Bs = cur + 4096;
        bf16x8 af[4], bfr[3];
#pragma unroll
        for (int mt = 0; mt < 4; ++mt)
            af[mt] = *(const bf16x8*)(As + (wr * 64 + mt * 16 + lr) * 32 + lq * 8);
#pragma unroll
        for (int nt = 0; nt < 3; ++nt)
            bfr[nt] = *(const bf16x8*)(Bs + (wc * 48 + nt * 16 + lr) * 32 + lq * 8);
#pragma unroll
        for (int mt = 0; mt < 4; ++mt)
#pragma unroll
            for (int nt = 0; nt < 3; ++nt)
                acc[mt][nt] = __builtin_amdgcn_mfma_f32_16x16x32_bf16(
                    af[mt], bfr[nt], acc[mt][nt], 0, 0, 0);

        u16* t = cur; cur = nxt; nxt = t;
    }
    __syncthreads();   // drain before epilogue LDS reuse

    // ---- epilogue ----  C/D layout: col = lane&15, row = (lane>>4)*4 + r
    u16* tb = (u16*)smem;   // [128][104] bf16 tile (26.6 KB)

    if constexpr (MODE == 0) {
#pragma unroll
        for (int nt = 0; nt < 3; ++nt) {
            int cl = wc * 48 + nt * 16 + lr;
            float bsum = bih[n0 + cl] + bhh[n0 + cl];
#pragma unroll
            for (int mt = 0; mt < 4; ++mt) {
                int rl = wr * 64 + mt * 16 + lq * 4;
                f32x4 v = acc[mt][nt];
#pragma unroll
                for (int r = 0; r < 4; ++r)
                    tb[(rl + r) * 104 + cl] = f2bf(v[r] + bsum);
            }
        }
        __syncthreads();
#pragma unroll
        for (int p = 0; p < 6; ++p) {
            int g = tid + p * 256;           // 1536 groups of 8 u16
            int row = g / 12, c8 = g % 12;
            u16x8 hv = *(const u16x8*)(tb + row * 104 + c8 * 8);
            *(u16x8*)(Out0 + (size_t)(m0 + row) * Dq + n0 + c8 * 8) = hv;       // Ub
            u16x8 hr;
#pragma unroll
            for (int k = 0; k < 8; ++k) hr[k] = (hv[k] & 0x8000u) ? (u16)0 : hv[k];
            *(u16x8*)(Out1 + (size_t)(m0 + row + Bq) * Dq + n0 + c8 * 8) = hr;  // Vpad
        }
    } else if constexpr (MODE == 1) {
#pragma unroll
        for (int p = 0; p < 6; ++p) {
            int g = tid + p * 256;
            int row = g / 12, c8 = g % 12;
            *(u16x8*)(tb + row * 104 + c8 * 8) =
                *(const u16x8*)(Ub_in + (size_t)(m0 + row) * Dq + n0 + c8 * 8);
        }
        __syncthreads();
#pragma unroll
        for (int nt = 0; nt < 3; ++nt) {
            int cl = wc * 48 + nt * 16 + lr;
#pragma unroll
            for (int mt = 0; mt < 4; ++mt) {
                int rl = wr * 64 + mt * 16 + lq * 4;
                f32x4 v = acc[mt][nt];
#pragma unroll
                for (int r = 0; r < 4; ++r) {
                    float gg = fmaxf(v[r] + bf2f(tb[(rl + r) * 104 + cl]), 0.f);
                    tb[(rl + r) * 104 + cl] = f2bf(gg);   // cell owned by this thread
                }
            }
        }
        __syncthreads();
#pragma unroll
        for (int p = 0; p < 6; ++p) {
            int g = tid + p * 256;
            int row = g / 12, c8 = g % 12;
            u16x8 hv = *(const u16x8*)(tb + row * 104 + c8 * 8);
            *(u16x8*)(Out0 + (size_t)(m0 + row + Bq) * Dq + n0 + c8 * 8) = hv;  // Gpad
        }
    } else {
        // MODE 2: fold Ub into acc, then transpose to [B,D,L] bf16 via LDS
#pragma unroll
        for (int p = 0; p < 6; ++p) {
            int g = tid + p * 256;
            int row = g / 12, c8 = g % 12;
            *(u16x8*)(tb + row * 104 + c8 * 8) =
                *(const u16x8*)(Ub_in + (size_t)(m0 + row) * Dq + n0 + c8 * 8);
        }
        __syncthreads();
#pragma unroll
        for (int nt = 0; nt < 3; ++nt) {
            int cl = wc * 48 + nt * 16 + lr;
#pragma unroll
            for (int mt = 0; mt < 4; ++mt) {
                int rl = wr * 64 + mt * 16 + lq * 4;
#pragma unroll
                for (int r = 0; r < 4; ++r)
                    acc[mt][nt][r] = fmaxf(acc[mt][nt][r] + bf2f(tb[(rl + r) * 104 + cl]), 0.f);
            }
        }
        __syncthreads();
        float* ep = (float*)smem;
        float* epw = ep + wave * (64 * 17);
        int l0w = (m0 >> 2) + wr * 16;   // wave covers 16 l values, 4 b values
#pragma unroll
        for (int nt = 0; nt < 3; ++nt) {
#pragma unroll
            for (int mt = 0; mt < 4; ++mt) {
                int lmb = mt * 16 + lq * 4;
                f32x4 v = acc[mt][nt];
#pragma unroll
                for (int r = 0; r < 4; ++r)
                    epw[(lmb + r) * 17 + lr] = v[r];
            }
            __syncthreads();
            int bb = lane >> 4, cc = lane & 15;
            int gnc = n0 + wc * 48 + nt * 16 + cc;
            float vals[16];
#pragma unroll
            for (int ll = 0; ll < 16; ++ll)
                vals[ll] = epw[(ll * 4 + bb) * 17 + cc];
            u16* dst = Out0 + (size_t)bb * (Dq * Lq) + (size_t)gnc * Lq + l0w;
            u16x8 h0, h1;
#pragma unroll
            for (int k = 0; k < 8; ++k) { h0[k] = f2bf(vals[k]); h1[k] = f2bf(vals[8 + k]); }
            *(u16x8*)dst = h0;
            *(u16x8*)(dst + 8) = h1;
            __syncthreads();
        }
    }
}

// ---- fused residual + LayerNorm over L (E is bf16 [B,D,L]) ----
__global__ __launch_bounds__(256) void ln_kernel(
    const u16* __restrict__ E, const float* __restrict__ x,
    const float* __restrict__ gamma, const float* __restrict__ beta,
    float* __restrict__ out) {
    __shared__ float red[2][4];
    size_t row = blockIdx.x;
    const u16x8* e8 = (const u16x8*)(E + row * Lq);
    const float* xr = x + row * Lq;
    float* o = out + row * Lq;
    int t = threadIdx.x;
    float z[16];
    float s = 0.f, sq = 0.f;
#pragma unroll
    for (int i = 0; i < 2; ++i) {
        int c = i * 256 + t;
        u16x8 ev = e8[c];
        f32x4 xv0 = *(const f32x4*)(xr + c * 8);
        f32x4 xv1 = *(const f32x4*)(xr + c * 8 + 4);
#pragma unroll
        for (int j = 0; j < 4; ++j) {
            float z0 = bf2f(ev[j]) + xv0[j];
            float z1 = bf2f(ev[4 + j]) + xv1[j];
            z[i * 8 + j] = z0;
            z[i * 8 + 4 + j] = z1;
            s += z0 + z1;
            sq += z0 * z0 + z1 * z1;
        }
    }
#pragma unroll
    for (int off = 32; off > 0; off >>= 1) {
        s += __shfl_down(s, off);
        sq += __shfl_down(sq, off);
    }
    int wave = t >> 6, lane = t & 63;
    if (lane == 0) { red[0][wave] = s; red[1][wave] = sq; }
    __syncthreads();
    s = red[0][0] + red[0][1] + red[0][2] + red[0][3];
    sq = red[1][0] + red[1][1] + red[1][2] + red[1][3];
    float mean = s * (1.f / Lq);
    float var = sq * (1.f / Lq) - mean * mean;
    float rstd = rsqrtf(var + 1e-12f);
#pragma unroll
    for (int i = 0; i < 2; ++i) {
        int c = i * 256 + t;
#pragma unroll
        for (int h = 0; h < 2; ++h) {
            int idx = c * 8 + h * 4;
            f32x4 gv = *(const f32x4*)(gamma + idx);
            f32x4 bv = *(const f32x4*)(beta + idx);
            f32x4 ov;
#pragma unroll
            for (int j = 0; j < 4; ++j)
                ov[j] = (z[i * 8 + h * 4 + j] - mean) * rstd * gv[j] + bv[j];
            *(f32x4*)(o + idx) = ov;
        }
    }
}

extern "C" void kernel_launch(void* const* d_in, const int* in_sizes, int n_in,
                              void* d_out, int out_size, void* d_ws, size_t ws_size,
                              hipStream_t stream) {
    const float* x     = (const float*)d_in[0];
    const float* Wih   = (const float*)d_in[1];
    const float* Whh   = (const float*)d_in[2];
    const float* bih   = (const float*)d_in[3];
    const float* bhh   = (const float*)d_in[4];
    const float* gamma = (const float*)d_in[5];
    const float* beta  = (const float*)d_in[6];
    float* out = (float*)d_out;

    char* ws = (char*)d_ws;
    u16* Xt    = (u16*)ws;   ws += (size_t)Mq * Dq * 2;          // 25.2 MB
    u16* Wihb  = (u16*)ws;   ws += (size_t)Dq * Dq * 2;
    u16* Whhb  = (u16*)ws;   ws += (size_t)Dq * Dq * 2;
    u16* Ub    = (u16*)ws;   ws += (size_t)Mq * Dq * 2;          // 25.2 MB
    u16* Vpad  = (u16*)ws;   ws += (size_t)(Mq + Bq) * Dq * 2;   // 25.2 MB
    u16* Gpad  = (u16*)ws;   ws += (size_t)(Mq + Bq) * Dq * 2;   // 25.2 MB
    u16* Eout  = (u16*)ws;   ws += (size_t)Mq * Dq * 2;          // 25.2 MB

    prep_kernel<<<dim3((Dq * Dq + 255) / 256), 256, 0, stream>>>(
        Wih, Whh, Wihb, Whhb, Vpad, Gpad);
    transpose_kernel<<<dim3(Lq / 64, Dq / 64, Bq), 256, 0, stream>>>(x, Xt);

    dim3 ggrid(Mq / 128, Dq / 96);   // (128, 8) = 1024 blocks = exactly 4/CU
    // pass A: Ub = X@Wih^T + bih + bhh ; Vpad = relu(Ub) shifted +4 rows
    gemm_kernel<0><<<ggrid, 256, 0, stream>>>(Xt,   Wihb, nullptr, Ub,  Vpad, bih, bhh);
    // pass B: Gpad = relu(Ub + Vprev@Whh^T) shifted +4 rows
    gemm_kernel<1><<<ggrid, 256, 0, stream>>>(Vpad, Whhb, Ub, Gpad, nullptr, bih, bhh);
    // pass C: Eout[B,D,L] = relu(Ub + Gprev@Whh^T), transposed, bf16
    gemm_kernel<2><<<ggrid, 256, 0, stream>>>(Gpad, Whhb, Ub, Eout, nullptr, bih, bhh);

    ln_kernel<<<dim3(Bq * Dq), 256, 0, stream>>>(Eout, x, gamma, beta, out);
}